// Round 3
// baseline (800.416 us; speedup 1.0000x reference)
//
#include <hip/hip_runtime.h>

#define SIZE_N 1024
#define DDIM   65536
#define D_TILE 32
#define S_CHUNK 64
#define NCHUNK (SIZE_N / S_CHUNK)   // 16
#define PITCH  (D_TILE + 1)         // 33: bank = (s + d) % 32 -> <=2-way aliasing (free)

#define INV2PI 0.15915494309189535f

// Hardware trig: v_sin_f32/v_cos_f32 compute sin/cos(2*pi*r); reduce with v_fract
// (valid for negatives). ~3 VALU ops vs ~30 for OCML. Validated round 2 (absmax 0.0039).
__device__ __forceinline__ float sin2pi(float r) {
    return __builtin_amdgcn_sinf(__builtin_amdgcn_fractf(r));
}
__device__ __forceinline__ float cos2pi(float r) {
    return __builtin_amdgcn_cosf(__builtin_amdgcn_fractf(r));
}

// 2048 blocks = exactly 8 blocks/CU; double-buffered 64x33 tile x2 = 16.9 KB/block.
__global__ __launch_bounds__(256, 8) void reghd_main(
    const float* __restrict__ x,
    const float* __restrict__ w,
    const float* __restrict__ bias,
    const float* __restrict__ alpha,
    const float* __restrict__ M,
    float* __restrict__ out)
{
    __shared__ float tile[2][S_CHUNK * PITCH];

    const int t      = threadIdx.x;
    const int lane16 = t & 15;          // s-quad index within row group
    const int grp    = t >> 4;          // 0..15; rows grp and grp+16
    const int d0     = blockIdx.x * D_TILE;
    const int sx     = lane16 * 4;

    // Phase B decomposition: idx = t + 256*p2 -> srow = (t>>5) + 8*p2, dl = t&31
    const int srow0 = t >> 5;
    const int dl    = t & 31;

    float* __restrict__ hvs = out + 1 + DDIM;   // hvs[s*DDIM + d]

    float acc0 = 0.f, acc1 = 0.f;

    // ---- prologue: chunk 0 w/bias into registers (2 rows x (w4,b4) = 16 VGPRs) ----
    float4 w4a = *reinterpret_cast<const float4*>(w    + (size_t)(d0 + grp)      * SIZE_N + sx);
    float4 b4a = *reinterpret_cast<const float4*>(bias + (size_t)(d0 + grp)      * SIZE_N + sx);
    float4 w4b = *reinterpret_cast<const float4*>(w    + (size_t)(d0 + grp + 16) * SIZE_N + sx);
    float4 b4b = *reinterpret_cast<const float4*>(bias + (size_t)(d0 + grp + 16) * SIZE_N + sx);

    #pragma unroll 2
    for (int c = 0; c < NCHUNK; ++c) {
        const int s0 = c * S_CHUNK;
        float* __restrict__ buf = tile[c & 1];

        // x/alpha quads: L1/L2-resident (shared by all blocks), cheap to reload per chunk
        const float4 x4 = *reinterpret_cast<const float4*>(x + s0 + sx);
        const float4 a4 = *reinterpret_cast<const float4*>(alpha + s0 + sx);
        const float xr0 = x4.x * INV2PI;
        const float xr1 = x4.y * INV2PI;
        const float xr2 = x4.z * INV2PI;
        const float xr3 = x4.w * INV2PI;

        // ---- Phase A: trig + LDS transpose + alpha-weighted row sums ----
        {
            const float r0 = xr0 * w4a.x, r1 = xr1 * w4a.y, r2 = xr2 * w4a.z, r3 = xr3 * w4a.w;
            const float e0 = cos2pi(fmaf(b4a.x, INV2PI, r0)) * sin2pi(r0);
            const float e1 = cos2pi(fmaf(b4a.y, INV2PI, r1)) * sin2pi(r1);
            const float e2 = cos2pi(fmaf(b4a.z, INV2PI, r2)) * sin2pi(r2);
            const float e3 = cos2pi(fmaf(b4a.w, INV2PI, r3)) * sin2pi(r3);
            buf[(sx + 0) * PITCH + grp] = e0;
            buf[(sx + 1) * PITCH + grp] = e1;
            buf[(sx + 2) * PITCH + grp] = e2;
            buf[(sx + 3) * PITCH + grp] = e3;
            acc0 += e0 * a4.x + e1 * a4.y + e2 * a4.z + e3 * a4.w;
        }
        {
            const float r0 = xr0 * w4b.x, r1 = xr1 * w4b.y, r2 = xr2 * w4b.z, r3 = xr3 * w4b.w;
            const float e0 = cos2pi(fmaf(b4b.x, INV2PI, r0)) * sin2pi(r0);
            const float e1 = cos2pi(fmaf(b4b.y, INV2PI, r1)) * sin2pi(r1);
            const float e2 = cos2pi(fmaf(b4b.z, INV2PI, r2)) * sin2pi(r2);
            const float e3 = cos2pi(fmaf(b4b.w, INV2PI, r3)) * sin2pi(r3);
            buf[(sx + 0) * PITCH + grp + 16] = e0;
            buf[(sx + 1) * PITCH + grp + 16] = e1;
            buf[(sx + 2) * PITCH + grp + 16] = e2;
            buf[(sx + 3) * PITCH + grp + 16] = e3;
            acc1 += e0 * a4.x + e1 * a4.y + e2 * a4.z + e3 * a4.w;
        }

        // ---- prefetch chunk c+1 BEFORE the barrier: latency hides under barrier
        // wait + phase B. Only 16 VGPRs. Tail clamps to a redundant L2-hit reload.
        const int s1 = (c + 1 < NCHUNK) ? (s0 + S_CHUNK) : s0;
        w4a = *reinterpret_cast<const float4*>(w    + (size_t)(d0 + grp)      * SIZE_N + s1 + sx);
        b4a = *reinterpret_cast<const float4*>(bias + (size_t)(d0 + grp)      * SIZE_N + s1 + sx);
        w4b = *reinterpret_cast<const float4*>(w    + (size_t)(d0 + grp + 16) * SIZE_N + s1 + sx);
        b4b = *reinterpret_cast<const float4*>(bias + (size_t)(d0 + grp + 16) * SIZE_N + s1 + sx);

        // LDS-only fence + raw barrier: prefetch loads and hvs stores stay in
        // flight across it (hipcc's __syncthreads would drain vmcnt(0) here).
        asm volatile("s_waitcnt lgkmcnt(0)\n\ts_barrier" ::: "memory");

        // ---- Phase B: coalesced transposed writes (two 128 B segments per wave).
        // Nontemporal: hvs is never re-read; don't evict w/bias from L2/L3.
        {
            const float* lsrc = buf + srow0 * PITCH + dl;
            float*       gdst = hvs + (size_t)(s0 + srow0) * DDIM + d0 + dl;
            #pragma unroll
            for (int p2 = 0; p2 < 8; ++p2) {
                __builtin_nontemporal_store(lsrc[p2 * 8 * PITCH], gdst);
                gdst += (size_t)8 * DDIM;
            }
        }
        // Buffer reuse at distance 2 is safe: A(c+2) happens after barrier(c+1),
        // which every thread reaches only after finishing B(c).
    }

    // ---- epilogue: bundled -> q, partial model_result = dot(q, M) ----
    float local_dot = 0.f;
    {
        float s = acc0;
        #pragma unroll
        for (int m = 1; m < 16; m <<= 1) s += __shfl_xor(s, m);
        if (lane16 == 0) {
            const int d = d0 + grp;
            const float qv = (s > 0.f) ? 1.f : -1.f;
            out[1 + d] = qv;
            local_dot += qv * M[d];
        }
    }
    {
        float s = acc1;
        #pragma unroll
        for (int m = 1; m < 16; m <<= 1) s += __shfl_xor(s, m);
        if (lane16 == 0) {
            const int d = d0 + grp + 16;
            const float qv = (s > 0.f) ? 1.f : -1.f;
            out[1 + d] = qv;
            local_dot += qv * M[d];
        }
    }
    // lanes 0,16,32,48 hold partials; fold to lane 0, one atomic per wave
    local_dot += __shfl_xor(local_dot, 16);
    local_dot += __shfl_xor(local_dot, 32);
    if ((t & 63) == 0) atomicAdd(out, local_dot);
}

extern "C" void kernel_launch(void* const* d_in, const int* in_sizes, int n_in,
                              void* d_out, int out_size, void* d_ws, size_t ws_size,
                              hipStream_t stream) {
    const float* x     = (const float*)d_in[0];
    const float* w     = (const float*)d_in[1];
    const float* bias  = (const float*)d_in[2];
    const float* alpha = (const float*)d_in[3];
    const float* M     = (const float*)d_in[4];
    float* out = (float*)d_out;

    // out[0] accumulates model_result via atomics; harness poisons d_out each call
    hipMemsetAsync(out, 0, sizeof(float), stream);

    reghd_main<<<dim3(DDIM / D_TILE), dim3(256), 0, stream>>>(x, w, bias, alpha, M, out);
}